// Round 8
// baseline (1146.504 us; speedup 1.0000x reference)
//
#include <hip/hip_runtime.h>
#include <math.h>

// BracketNet: ctx_{s+1} = GELU_exact(Wc·ctx_s + (b + Wx·x_s)); out_s = x_s + ctx_{s+1}
// pass1: z = b + Wx·x, parallel readlane-GEMV, 8192 waves (chunks of 128 s).
// pass2: serial chain, one wave per (b,h); per-step matvec y = Wc·g via
//        8x mfma_f32_16x16x32_f16 (A = g replicated across rows, f16; z added
//        in fp32 after). Cross-lane staging with ds_bpermute (no SGPR hazard).
//
// Round-7 lesson: 64x v_readlane->v_fma(sgpr) per step = VALU->SGPR->VALU
// hazard chain, ~808 cyc/step measured vs ~330 issue. MFMA does the cross-lane
// reduction in hardware. Layout safety: A and B fragments are packed with the
// SAME slot->k bijection, so the dot product is correct under ANY hardware
// k-map (permutation invariance); only the C-map (col=lane&15, verified) is
// load-bearing.

typedef float    f32x4 __attribute__((ext_vector_type(4)));
typedef int      i32x4 __attribute__((ext_vector_type(4)));
typedef _Float16 f16x8 __attribute__((ext_vector_type(8)));
typedef _Float16 f16x2 __attribute__((ext_vector_type(2)));

#define S_LEN 2048
#define B_SZ  64
#define D_SZ  512
#define DIM   64
#define STRIDE ((size_t)(B_SZ * D_SZ))   // floats between consecutive s

// Branchless exact-GELU: 0.5*y*(1+erf(y/sqrt2)), erf via A&S 7.1.26 (|eps|<=1.5e-7).
__device__ __forceinline__ float gelu_exact(float y) {
    const float ax = fabsf(y) * 0.70710678118654752440f;     // |y|/sqrt(2)
    const float t  = __builtin_amdgcn_rcpf(fmaf(0.3275911f, ax, 1.0f));
    float p = fmaf(1.061405429f, t, -1.453152027f);
    p = fmaf(p, t, 1.421413741f);
    p = fmaf(p, t, -0.284496736f);
    p = fmaf(p, t, 0.254829592f);
    p *= t;
    const float e = __builtin_amdgcn_exp2f(-ax * ax * 1.44269504088896f);
    float er = fmaf(-p, e, 1.0f);                            // erf(|x|)
    er = copysignf(er, y);
    return 0.5f * y * (1.0f + er);
}

// ---------------- Pass 1: readlane-GEMV (unchanged structure, 4x more waves).
#define RL(k, comp, accn)                                                     \
    a##accn = fmaf(__int_as_float(__builtin_amdgcn_readlane(gi, (k))),        \
                   w[(k) >> 2].comp, a##accn)
#define G8(m)                                                                 \
    RL(8 * m + 0, x, 0); RL(8 * m + 1, y, 1); RL(8 * m + 2, z, 2);            \
    RL(8 * m + 3, w, 3); RL(8 * m + 4, x, 4); RL(8 * m + 5, y, 5);            \
    RL(8 * m + 6, z, 6); RL(8 * m + 7, w, 7);
#define G64_REDUCE(y)                                                         \
    G8(0); G8(1); G8(2); G8(3); G8(4); G8(5); G8(6); G8(7);                   \
    const float y = ((a0 + a1) + (a2 + a3)) + ((a4 + a5) + (a6 + a7));

__global__ __launch_bounds__(64, 1) void bracket_pass1(
    const float* __restrict__ src, const float* __restrict__ W,
    const float* __restrict__ bias, float* __restrict__ zout)
{
    const int lane = threadIdx.x;
    const int ck   = blockIdx.x >> 9;          // 0..15 (128 s each)
    const int bb   = (blockIdx.x >> 3) & 63;
    const int hh   = blockIdx.x & 7;

    f32x4 w[16];
    {
        const float* wb = W + (size_t)(hh * DIM + lane) * (2 * DIM) + DIM;
#pragma unroll
        for (int i = 0; i < 16; ++i)
            asm volatile("global_load_dwordx4 %0, %1, off offset:%2"
                         : "=v"(w[i]) : "v"(wb), "i"(16 * i));
    }
    asm volatile("s_waitcnt vmcnt(0)" ::: "memory");
    __builtin_amdgcn_sched_barrier(0);

    const float bv = bias[hh * DIM + lane];

    const float* sp = src  + (size_t)(ck * 128) * STRIDE + (size_t)bb * D_SZ + hh * DIM + lane;
    float*       zp = zout + (size_t)(ck * 128) * STRIDE + (size_t)bb * D_SZ + hh * DIM + lane;

    float x0 = sp[0], x1 = sp[STRIDE], x2 = sp[2 * STRIDE], x3 = sp[3 * STRIDE];
    const float* pp = sp + 4 * STRIDE;

#define P1STEP(xc)                                                            \
    do {                                                                      \
        const int gi = __float_as_int(xc);                                    \
        float a0 = bv, a1 = 0.f, a2 = 0.f, a3 = 0.f;                          \
        float a4 = 0.f, a5 = 0.f, a6 = 0.f, a7 = 0.f;                         \
        G64_REDUCE(y);                                                        \
        *zp = y;                                                              \
        zp += STRIDE;                                                         \
    } while (0)

    for (int i = 0; i < 124; i += 4) {
        float xn;
        xn = *pp; pp += STRIDE; P1STEP(x0); x0 = xn;
        xn = *pp; pp += STRIDE; P1STEP(x1); x1 = xn;
        xn = *pp; pp += STRIDE; P1STEP(x2); x2 = xn;
        xn = *pp; pp += STRIDE; P1STEP(x3); x3 = xn;
    }
    P1STEP(x0); P1STEP(x1); P1STEP(x2); P1STEP(x3);
#undef P1STEP
}

// ---------------- Pass 2: serial chain via MFMA.
__global__ __launch_bounds__(64, 1) void bracket_pass2(
    const float* __restrict__ src, const float* __restrict__ W,
    float* __restrict__ out)   // out holds z on entry; overwritten with result
{
    const int lane = threadIdx.x;
    const int bb   = blockIdx.x >> 3;
    const int hh   = blockIdx.x & 7;
    const int q    = lane >> 4;        // 0..3
    const int c    = lane & 15;        // 0..15

    // B fragments: tile t covers output dims t*16..t*16+15; K-chunk K covers
    // k = K*32..K*32+31. Slot (q, j=2dw+h) holds Wc[t*16+c][K*32 + q*8 + j],
    // packed lo/hi per dword — the SAME bijection used for the A gather.
    f16x8 bf0[4], bf1[4];
    {
        const float* Wh = W + (size_t)hh * DIM * (2 * DIM);
#pragma unroll
        for (int t = 0; t < 4; ++t) {
            const float* wr = Wh + (size_t)(t * 16 + c) * (2 * DIM);
#pragma unroll
            for (int K = 0; K < 2; ++K) {
                i32x4 di;
#pragma unroll
                for (int dw = 0; dw < 4; ++dw) {
                    const float* p2 = wr + K * 32 + q * 8 + 2 * dw;
                    di[dw] = __builtin_bit_cast(
                        int, __builtin_amdgcn_cvt_pkrtz(p2[0], p2[1]));
                }
                if (K == 0) bf0[t] = __builtin_bit_cast(f16x8, di);
                else        bf1[t] = __builtin_bit_cast(f16x8, di);
            }
        }
    }

    // bpermute byte addresses (constant per lane).
    int aG[16];
#pragma unroll
    for (int j = 0; j < 8; ++j) { aG[j] = (q * 8 + j) * 4; aG[j + 8] = aG[j] + 128; }
    int aZ[4];
#pragma unroll
    for (int t = 0; t < 4; ++t) aZ[t] = (t * 16 + c) * 4;

    const bool qo = (q & 1) != 0;
    const bool q2 = (q & 2) != 0;

    const float* sp = src + (size_t)bb * D_SZ + hh * DIM + lane;
    float*       op = out + (size_t)bb * D_SZ + hh * DIM + lane;

    // Depth-8 prefetch pipelines (x from src, z from out).
    float xb[8], zb[8];
#pragma unroll
    for (int i = 0; i < 8; ++i) { xb[i] = sp[(size_t)i * STRIDE]; zb[i] = op[(size_t)i * STRIDE]; }
    const float* px  = sp + 8 * STRIDE;
    const float* pz  = op + 8 * STRIDE;
    const float* pxl = sp + (size_t)(S_LEN - 1) * STRIDE;
    const float* pzl = op + (size_t)(S_LEN - 1) * STRIDE;

    float g4_0 = 0.f, g4_1 = 0.f, g4_2 = 0.f, g4_3 = 0.f;  // g[t*16+c]
    float gg = 0.f;                                         // flat: g[lane]
    const f32x4 zero = {0.f, 0.f, 0.f, 0.f};

    for (int s = 0; s < S_LEN; s += 8) {
#pragma unroll
        for (int i = 0; i < 8; ++i) {
            // ---- gather A slots from flat g (ctx_s): slot j <- g[q*8+j(+32)]
            const int ggi = __builtin_bit_cast(int, gg);
            int r[16];
#pragma unroll
            for (int j = 0; j < 16; ++j)
                r[j] = __builtin_amdgcn_ds_bpermute(aG[j], ggi);
            i32x4 A1i, A2i;
#pragma unroll
            for (int dw = 0; dw < 4; ++dw) {
                A1i[dw] = __builtin_bit_cast(int, __builtin_amdgcn_cvt_pkrtz(
                    __builtin_bit_cast(float, r[2 * dw]),
                    __builtin_bit_cast(float, r[2 * dw + 1])));
                A2i[dw] = __builtin_bit_cast(int, __builtin_amdgcn_cvt_pkrtz(
                    __builtin_bit_cast(float, r[8 + 2 * dw]),
                    __builtin_bit_cast(float, r[8 + 2 * dw + 1])));
            }
            const f16x8 A1 = __builtin_bit_cast(f16x8, A1i);
            const f16x8 A2 = __builtin_bit_cast(f16x8, A2i);

            // ---- z for this step, redistributed: z4[t] = z[t*16+c]
            const int zi = __builtin_bit_cast(int, zb[i]);
            const float z4_0 = __builtin_bit_cast(float, __builtin_amdgcn_ds_bpermute(aZ[0], zi));
            const float z4_1 = __builtin_bit_cast(float, __builtin_amdgcn_ds_bpermute(aZ[1], zi));
            const float z4_2 = __builtin_bit_cast(float, __builtin_amdgcn_ds_bpermute(aZ[2], zi));
            const float z4_3 = __builtin_bit_cast(float, __builtin_amdgcn_ds_bpermute(aZ[3], zi));

            // ---- y = Wc·g (8 MFMAs); rows replicated -> result in reg 0.
            f32x4 ac0 = __builtin_amdgcn_mfma_f32_16x16x32_f16(A1, bf0[0], zero, 0, 0, 0);
            f32x4 ac1 = __builtin_amdgcn_mfma_f32_16x16x32_f16(A1, bf0[1], zero, 0, 0, 0);
            f32x4 ac2 = __builtin_amdgcn_mfma_f32_16x16x32_f16(A1, bf0[2], zero, 0, 0, 0);
            f32x4 ac3 = __builtin_amdgcn_mfma_f32_16x16x32_f16(A1, bf0[3], zero, 0, 0, 0);
            ac0 = __builtin_amdgcn_mfma_f32_16x16x32_f16(A2, bf1[0], ac0, 0, 0, 0);
            ac1 = __builtin_amdgcn_mfma_f32_16x16x32_f16(A2, bf1[1], ac1, 0, 0, 0);
            ac2 = __builtin_amdgcn_mfma_f32_16x16x32_f16(A2, bf1[2], ac2, 0, 0, 0);
            ac3 = __builtin_amdgcn_mfma_f32_16x16x32_f16(A2, bf1[3], ac3, 0, 0, 0);

            // ---- gelu -> ctx_{s+1}
            g4_0 = gelu_exact(ac0[0] + z4_0);
            g4_1 = gelu_exact(ac1[0] + z4_1);
            g4_2 = gelu_exact(ac2[0] + z4_2);
            g4_3 = gelu_exact(ac3[0] + z4_3);

            // ---- flatten to g[lane] (feeds both the store and next gather)
            const float t0 = qo ? g4_1 : g4_0;
            const float t1 = qo ? g4_3 : g4_2;
            gg = q2 ? t1 : t0;

            // ---- out[s] = x[s] + ctx_{s+1}
            *op = xb[i] + gg;
            op += STRIDE;

            // ---- prefetch s+8
            xb[i] = *px;
            zb[i] = *pz;
            px = (px < pxl) ? px + STRIDE : pxl;
            pz = (pz < pzl) ? pz + STRIDE : pzl;
        }
    }
}

extern "C" void kernel_launch(void* const* d_in, const int* in_sizes, int n_in,
                              void* d_out, int out_size, void* d_ws, size_t ws_size,
                              hipStream_t stream) {
    const float* src = (const float*)d_in[0];
    const float* W   = (const float*)d_in[1];
    const float* b   = (const float*)d_in[2];
    float* out       = (float*)d_out;

    hipLaunchKernelGGL(bracket_pass1, dim3(B_SZ * 8 * 16), dim3(64), 0, stream,
                       src, W, b, out);
    hipLaunchKernelGGL(bracket_pass2, dim3(B_SZ * 8), dim3(64), 0, stream,
                       src, W, out);
}

// Round 9
// 1126.497 us; speedup vs baseline: 1.0178x; 1.0178x over previous
//
#include <hip/hip_runtime.h>
#include <math.h>

// BracketNet: ctx_{s+1} = GELU_exact(Wc·ctx_s + (b + Wx·x_s)); out_s = x_s + ctx_{s+1}
// pass1: z = b + Wx·x, parallel, one wave per (b,h,128-s chunk).
// pass2: serial chain, one wave per (b,h).
// Both use the same matvec core: stage the 64-wide vector in LDS (1 ds_write),
// read it back as 16 uniform-address ds_read_b128 (hardware broadcast), and
// run 64 v_fma against the asm-pinned 64-VGPR weight row.
//
// Round-8 lesson: MFMA matvec lost to readlane (1078 vs 808 cyc/step) — the
// 20 ds_bpermute gathers + f16 packing per step cost more than the MFMAs
// saved. Round-7 lesson: 64x readlane->fma(sgpr) = ~6 cyc/pair SGPR hazard.
// Uniform-address ds_read_b128 broadcast avoids both: VGPR operands, 16 DS
// ops, no per-element cross-lane traffic.

typedef float f32x4 __attribute__((ext_vector_type(4)));

#define S_LEN 2048
#define B_SZ  64
#define D_SZ  512
#define DIM   64
#define STRIDE ((size_t)(B_SZ * D_SZ))   // floats between consecutive s

// Branchless exact-GELU: 0.5*y*(1+erf(y/sqrt2)), erf via A&S 7.1.26 (|eps|<=1.5e-7).
__device__ __forceinline__ float gelu_exact(float y) {
    const float ax = fabsf(y) * 0.70710678118654752440f;     // |y|/sqrt(2)
    const float t  = __builtin_amdgcn_rcpf(fmaf(0.3275911f, ax, 1.0f));
    float p = fmaf(1.061405429f, t, -1.453152027f);
    p = fmaf(p, t, 1.421413741f);
    p = fmaf(p, t, -0.284496736f);
    p = fmaf(p, t, 0.254829592f);
    p *= t;
    const float e = __builtin_amdgcn_exp2f(-ax * ax * 1.44269504088896f);
    float er = fmaf(-p, e, 1.0f);                            // erf(|x|)
    er = copysignf(er, y);
    return 0.5f * y * (1.0f + er);
}

// y[lane] = base + sum_k w[lane][k] * vv[k]; vv = uniform LDS pointer
// (all lanes same address -> broadcast, conflict-free ds_read_b128).
__device__ __forceinline__ float gemv64(const f32x4* vv, const f32x4 (&w)[16],
                                        float base) {
    float a0 = base, a1 = 0.f, a2 = 0.f, a3 = 0.f;
    float a4 = 0.f, a5 = 0.f, a6 = 0.f, a7 = 0.f;
#pragma unroll
    for (int j = 0; j < 16; j += 2) {
        const f32x4 u0 = vv[j], u1 = vv[j + 1];
        a0 = fmaf(w[j].x,     u0.x, a0);
        a1 = fmaf(w[j].y,     u0.y, a1);
        a2 = fmaf(w[j].z,     u0.z, a2);
        a3 = fmaf(w[j].w,     u0.w, a3);
        a4 = fmaf(w[j + 1].x, u1.x, a4);
        a5 = fmaf(w[j + 1].y, u1.y, a5);
        a6 = fmaf(w[j + 1].z, u1.z, a6);
        a7 = fmaf(w[j + 1].w, u1.w, a7);
    }
    return ((a0 + a1) + (a2 + a3)) + ((a4 + a5) + (a6 + a7));
}

// ---------------- Pass 1: z[s,b,h,d] = bias[h,d] + sum_k Wx[h,d,k] x[s,b,h,k]
// One wave per (b,h,chunk of 128 s); 8192 blocks.
__global__ __launch_bounds__(64, 1) void bracket_pass1(
    const float* __restrict__ src, const float* __restrict__ W,
    const float* __restrict__ bias, float* __restrict__ zout)
{
    const int lane = threadIdx.x;
    const int ck   = blockIdx.x >> 9;          // 0..15 (128 s each)
    const int bb   = (blockIdx.x >> 3) & 63;
    const int hh   = blockIdx.x & 7;

    f32x4 w[16];
    {
        const float* wb = W + (size_t)(hh * DIM + lane) * (2 * DIM) + DIM;
#pragma unroll
        for (int i = 0; i < 16; ++i)
            asm volatile("global_load_dwordx4 %0, %1, off offset:%2"
                         : "=v"(w[i]) : "v"(wb), "i"(16 * i));
    }
    asm volatile("s_waitcnt vmcnt(0)" ::: "memory");
    __builtin_amdgcn_sched_barrier(0);

    const float bv = bias[hh * DIM + lane];

    __shared__ __align__(16) float xsl[2][DIM];   // 512 B ping-pong

    const float* sp = src  + (size_t)(ck * 128) * STRIDE + (size_t)bb * D_SZ + hh * DIM + lane;
    float*       zp = zout + (size_t)(ck * 128) * STRIDE + (size_t)bb * D_SZ + hh * DIM + lane;

    float x0 = sp[0], x1 = sp[STRIDE];
    const float* pp    = sp + 2 * STRIDE;
    const float* plast = sp + 127 * STRIDE;

#define P1STEP(cur, xc)                                                       \
    do {                                                                      \
        xsl[cur][lane] = xc;                   /* ds_write_b32 */             \
        const float xn = *pp;                  /* fire-and-forget prefetch */ \
        pp = (pp < plast) ? (pp + STRIDE) : plast;                            \
        const float y = gemv64((const f32x4*)xsl[cur], w, bv);                \
        *zp = y;                                                              \
        zp += STRIDE;                                                         \
        xc = xn;                                                              \
    } while (0)

    for (int i = 0; i < 128; i += 2) {
        P1STEP(0, x0);
        P1STEP(1, x1);
    }
#undef P1STEP
}

// ---------------- Pass 2: the serial recurrence, one wave per (b,h) chain.
__global__ __launch_bounds__(64, 1) void bracket_pass2(
    const float* __restrict__ src, const float* __restrict__ W,
    float* __restrict__ out)   // out holds z on entry; overwritten with result
{
    const int lane = threadIdx.x;
    const int bb   = blockIdx.x >> 3;
    const int hh   = blockIdx.x & 7;

    // Wc row: 16 float4 = 64 VGPRs, pinned (volatile asm, non-rematerializable).
    f32x4 w[16];
    {
        const float* wb = W + (size_t)(hh * DIM + lane) * (2 * DIM);
#pragma unroll
        for (int i = 0; i < 16; ++i)
            asm volatile("global_load_dwordx4 %0, %1, off offset:%2"
                         : "=v"(w[i]) : "v"(wb), "i"(16 * i));
    }
    asm volatile("s_waitcnt vmcnt(0)" ::: "memory");
    __builtin_amdgcn_sched_barrier(0);

    __shared__ __align__(16) float gsl[2][DIM];   // 512 B ping-pong

    const float* sp = src + (size_t)bb * D_SZ + hh * DIM + lane;
    float*       op = out + (size_t)bb * D_SZ + hh * DIM + lane;

    // Depth-8 prefetch pipelines (x from src, z from out).
    float xb[8], zb[8];
#pragma unroll
    for (int i = 0; i < 8; ++i) {
        xb[i] = sp[(size_t)i * STRIDE];
        zb[i] = op[(size_t)i * STRIDE];
    }
    const float* px  = sp + 8 * STRIDE;
    const float* pz  = op + 8 * STRIDE;
    const float* pxl = sp + (size_t)(S_LEN - 1) * STRIDE;
    const float* pzl = op + (size_t)(S_LEN - 1) * STRIDE;

    float g = 0.0f;   // ctx_0 = 0

    for (int s = 0; s < S_LEN; s += 8) {
#pragma unroll
        for (int i = 0; i < 8; ++i) {
            const int cur = i & 1;
            gsl[cur][lane] = g;                  // ds_write_b32 (serial path)

            // Off-path: issue next prefetches while the write lands.
            const float xn = *px;
            const float zn = *pz;
            px = (px < pxl) ? px + STRIDE : pxl;
            pz = (pz < pzl) ? pz + STRIDE : pzl;

            // y = z + Wc·g   (16 broadcast ds_read_b128 + 64 v_fma)
            const float y = gemv64((const f32x4*)gsl[cur], w, zb[i]);
            g = gelu_exact(y);

            *op = xb[i] + g;                     // out = x + ctx (off-path)
            op += STRIDE;

            xb[i] = xn;
            zb[i] = zn;
        }
    }
}

extern "C" void kernel_launch(void* const* d_in, const int* in_sizes, int n_in,
                              void* d_out, int out_size, void* d_ws, size_t ws_size,
                              hipStream_t stream) {
    const float* src = (const float*)d_in[0];
    const float* W   = (const float*)d_in[1];
    const float* b   = (const float*)d_in[2];
    float* out       = (float*)d_out;

    hipLaunchKernelGGL(bracket_pass1, dim3(B_SZ * 8 * 16), dim3(64), 0, stream,
                       src, W, b, out);
    hipLaunchKernelGGL(bracket_pass2, dim3(B_SZ * 8), dim3(64), 0, stream,
                       src, W, out);
}